// Round 1
// 144.766 us; speedup vs baseline: 1.0691x; 1.0691x over previous
//
#include <hip/hip_runtime.h>
#include <hip/hip_bf16.h>

using bf16 = __hip_bfloat16;
typedef __attribute__((ext_vector_type(8))) short short8;
typedef __attribute__((ext_vector_type(4))) float floatx4;

#define B_      32
#define HH      56
#define WW      56
#define HIDDEN  96
#define HEADS   3
#define HD      32
#define WS_     7
#define DISP    3
#define NWH     8
#define NWW     8
#define NW      64
#define WS2     49
#define NFRAG_QKV (3*6*3*64)                      /* 3456 lane-frags */
#define NFRAG_OUT (6*3*64)                        /* 1152 lane-frags */

// ---------------- Kernel 0: weight pre-swizzle into MFMA B-frag order -----
// wf[t*64+lane] (short8) = B-fragment for frag-tile t, lane l.
// qkv: t = (ci*6+c6)*3+kb, frag[j] = w_qkv[(kb*32+rowq*8+j)*288 + ci*96+c6*16+n_]
// out: t = c6*3+kb,        frag[j] = w_out [(kb*32+rowq*8+j)*96  + c6*16+n_]
__global__ __launch_bounds__(256) void prep_weights_kernel(
    const float* __restrict__ w_qkv, const float* __restrict__ w_out,
    bf16* __restrict__ wfq, bf16* __restrict__ wfo) {
  int f = blockIdx.x * 256 + threadIdx.x;
  if (f < NFRAG_QKV) {
    int lane = f & 63, t = f >> 6;
    int kb = t % 3, t2 = t / 3, c6 = t2 % 6, ci = t2 / 6;
    int col = ci * 96 + c6 * 16 + (lane & 15);
    int k0 = kb * 32 + (lane >> 4) * 8;
    bf16 vals[8];
#pragma unroll
    for (int j = 0; j < 8; j++) vals[j] = __float2bfloat16(w_qkv[(k0 + j) * 288 + col]);
    *(short8*)&wfq[(size_t)f * 8] = *(const short8*)vals;
  } else if (f < NFRAG_QKV + NFRAG_OUT) {
    int fo = f - NFRAG_QKV;
    int lane = fo & 63, t = fo >> 6;
    int kb = t % 3, c6 = t / 3;
    int col = c6 * 16 + (lane & 15);
    int k0 = kb * 32 + (lane >> 4) * 8;
    bf16 vals[8];
#pragma unroll
    for (int j = 0; j < 8; j++) vals[j] = __float2bfloat16(w_out[(k0 + j) * 96 + col]);
    *(short8*)&wfo[(size_t)fo * 8] = *(const short8*)vals;
  }
}

__device__ inline unsigned short bf16_bits(float f) {
  unsigned u = __float_as_uint(f);
  unsigned r = u + 0x7fffu + ((u >> 16) & 1u);
  return (unsigned short)(r >> 16);
}

// ---------------- Fused kernel: one block per (batch, window) -------------
// Phases: stage x(shifted) -> QKV MFMA (n-split over waves) -> per-head
// attention (m-split) -> out-proj MFMA (n-split) -> scattered f32 store.
// LDS reuse: slabA holds x-staging, then q, then attention output.
// Total static LDS = 15360+15360+16896+11264+676 = 59,556 B (2 blocks/CU).
__global__ __launch_bounds__(256) void fused_swin_kernel(
    const float* __restrict__ x,
    const bf16* __restrict__ wfq, const bf16* __restrict__ wfo,
    const float* __restrict__ b_qkv, const float* __restrict__ b_out,
    const float* __restrict__ pos_emb, float* __restrict__ out) {

  __shared__ unsigned short slabA[3][64][40];  // x (by 32-ch group) -> q3 -> attn out
  __shared__ unsigned short slabB[3][64][40];  // k3 (per head, [tok][d])
  __shared__ unsigned short vT[3][32][88];     // v transposed (per head, [d][tok])
  __shared__ unsigned short es[64][88];        // softmax probs (per-wave-private rows)
  __shared__ float pel[169];

  const int blk = blockIdx.x;
  const int nw = blk & 63, b = blk >> 6;
  const int wy = nw >> 3, wx = nw & 7;
  const int tid = threadIdx.x;
  const int lane = tid & 63, wv = tid >> 6;
  const int n_ = lane & 15, quad = lane >> 4;

  // ---- phase 1: shifted gather of x into slabA, 49 rows + zero pad ----
  for (int idx = tid; idx < 64 * 24; idx += 256) {
    int tl = idx / 24, seg = idx % 24;
    int kb = seg >> 3, c4 = (seg & 7) << 2;
    ushort4 pk;
    if (tl < WS2) {
      int py = tl / WS_, px = tl % WS_;
      int h = wy * WS_ + py + DISP; if (h >= HH) h -= HH;
      int w = wx * WS_ + px + DISP; if (w >= WW) w -= WW;
      const float4 xv = *(const float4*)&x[((size_t)(b * HH + h) * WW + w) * HIDDEN + seg * 4];
      pk.x = bf16_bits(xv.x); pk.y = bf16_bits(xv.y);
      pk.z = bf16_bits(xv.z); pk.w = bf16_bits(xv.w);
    } else {
      pk.x = 0; pk.y = 0; pk.z = 0; pk.w = 0;  // pad rows: finite downstream
    }
    *(ushort4*)&slabA[kb][tl][c4] = pk;
  }
  for (int i = tid; i < 169; i += 256) pel[i] = pos_emb[i];
  __syncthreads();

  // ---- phase 2a: every wave reads A-frags for all 4 m-tiles ----
  short8 af[4][3];
#pragma unroll
  for (int m = 0; m < 4; m++)
#pragma unroll
    for (int kb = 0; kb < 3; kb++)
      af[m][kb] = *(const short8*)&slabA[kb][16 * m + n_][quad * 8];
  __syncthreads();  // slabA about to be overwritten by q

  // ---- phase 2b: QKV projection, N-split (tile t = ci*6+c6, wave = t%4) --
  {
    const short8* wfQ = (const short8*)wfq;
    for (int t = wv; t < 18; t += 4) {
      const int ci = t / 6, c6 = t % 6;
      const int head = c6 >> 1, dc = ((c6 & 1) << 4) + n_;
      const float bias = b_qkv[t * 16 + n_];
      floatx4 acc[4];
#pragma unroll
      for (int m = 0; m < 4; m++) acc[m] = (floatx4){bias, bias, bias, bias};
#pragma unroll
      for (int kb = 0; kb < 3; kb++) {
        const short8 bfr = wfQ[(size_t)((t * 3 + kb) * 64 + lane)];
#pragma unroll
        for (int m = 0; m < 4; m++)
          acc[m] = __builtin_amdgcn_mfma_f32_16x16x32_bf16(af[m][kb], bfr, acc[m], 0, 0, 0);
      }
      if (ci == 2) {           // v: store transposed [d][tok]
#pragma unroll
        for (int m = 0; m < 4; m++)
#pragma unroll
          for (int r = 0; r < 4; r++)
            vT[head][dc][16 * m + 4 * quad + r] = bf16_bits(acc[m][r]);
      } else {                 // q -> slabA, k -> slabB, [tok][d]
        unsigned short (*tgt)[64][40] = (ci == 0) ? slabA : slabB;
#pragma unroll
        for (int m = 0; m < 4; m++)
#pragma unroll
          for (int r = 0; r < 4; r++)
            tgt[head][16 * m + 4 * quad + r][dc] = bf16_bits(acc[m][r]);
      }
    }
  }
  __syncthreads();

  // ---- geometry: pos-emb + mask folded per lane, reused for all 3 heads --
  const bool maskedw = (nw >= NW - NWW);
  const int i0 = 16 * wv + 4 * quad;
  float pelv[4][4];
#pragma unroll
  for (int r = 0; r < 4; r++) {
    const int i_r = i0 + r;
    const int iy = i_r / WS_, ix = i_r % WS_;
#pragma unroll
    for (int jt = 0; jt < 4; jt++) {
      const int j = 16 * jt + n_;
      const int jy = j / WS_, jx = j % WS_;
      int idx = (jy - iy + 6) * 13 + (jx - ix + 6);
      idx = idx < 0 ? 0 : (idx > 168 ? 168 : idx);
      const bool live = (j < WS2) && (i_r < WS2) &&
                        !(maskedw && ((i_r >= 28) != (j >= 28)));
      pelv[r][jt] = live ? pel[idx] : -1e30f;
    }
  }

  // ---- phase 3: attention per head (waves m-split) ----
  const float scale = 0.10206207261596575f;  // 96^-0.5
  const floatx4 zero4 = (floatx4){0.f, 0.f, 0.f, 0.f};
  for (int h = 0; h < HEADS; h++) {
    const short8 aq = *(const short8*)&slabA[h][16 * wv + n_][quad * 8];
    floatx4 sAcc[4];
#pragma unroll
    for (int jt = 0; jt < 4; jt++) {
      const short8 bk = *(const short8*)&slabB[h][16 * jt + n_][quad * 8];
      sAcc[jt] = __builtin_amdgcn_mfma_f32_16x16x32_bf16(aq, bk, zero4, 0, 0, 0);
    }
    __syncthreads();  // all q[h] reads done before attn-out overwrites slabA[h]

    float ei[4][4], rowsum[4];
#pragma unroll
    for (int r = 0; r < 4; r++) {
      rowsum[r] = 0.f;
#pragma unroll
      for (int jt = 0; jt < 4; jt++) {
        const float e = __expf(fmaf(sAcc[jt][r], scale, pelv[r][jt]));
        ei[r][jt] = e;
        rowsum[r] += e;
      }
    }
#pragma unroll
    for (int r = 0; r < 4; r++) {
      float s = rowsum[r];
      s += __shfl_xor(s, 1); s += __shfl_xor(s, 2);
      s += __shfl_xor(s, 4); s += __shfl_xor(s, 8);
      const float inv = s > 0.f ? 1.0f / s : 0.f;
#pragma unroll
      for (int jt = 0; jt < 4; jt++)
        es[i0 + r][16 * jt + n_] = bf16_bits(ei[r][jt] * inv);
    }

    // PV: es rows are per-wave-private -> no barrier needed
    short8 ap[2];
#pragma unroll
    for (int kc = 0; kc < 2; kc++)
      ap[kc] = *(const short8*)&es[16 * wv + n_][32 * kc + quad * 8];
    floatx4 oAcc[2] = {zero4, zero4};
#pragma unroll
    for (int nt = 0; nt < 2; nt++)
#pragma unroll
      for (int kc = 0; kc < 2; kc++) {
        const short8 bv = *(const short8*)&vT[h][16 * nt + n_][32 * kc + quad * 8];
        oAcc[nt] = __builtin_amdgcn_mfma_f32_16x16x32_bf16(ap[kc], bv, oAcc[nt], 0, 0, 0);
      }
#pragma unroll
    for (int nt = 0; nt < 2; nt++)
#pragma unroll
      for (int r = 0; r < 4; r++)
        slabA[h][i0 + r][16 * nt + n_] = bf16_bits(oAcc[nt][r]);
  }
  __syncthreads();

  // ---- phase 4: output projection, N-split, scattered f32 store ----
  short8 af2[4][3];
#pragma unroll
  for (int m = 0; m < 4; m++)
#pragma unroll
    for (int kb = 0; kb < 3; kb++)
      af2[m][kb] = *(const short8*)&slabA[kb][16 * m + n_][quad * 8];

  const short8* wfO = (const short8*)wfo;
  for (int t = wv; t < 6; t += 4) {
    const float bias = b_out[t * 16 + n_];
    floatx4 acc[4];
#pragma unroll
    for (int m = 0; m < 4; m++) acc[m] = (floatx4){bias, bias, bias, bias};
#pragma unroll
    for (int kb = 0; kb < 3; kb++) {
      const short8 bfr = wfO[(size_t)((t * 3 + kb) * 64 + lane)];
#pragma unroll
      for (int m = 0; m < 4; m++)
        acc[m] = __builtin_amdgcn_mfma_f32_16x16x32_bf16(af2[m][kb], bfr, acc[m], 0, 0, 0);
    }
#pragma unroll
    for (int m = 0; m < 4; m++)
#pragma unroll
      for (int r = 0; r < 4; r++) {
        const int row = 16 * m + 4 * quad + r;
        if (row < WS2) {
          const int py = row / WS_, px = row % WS_;
          int hg = wy * WS_ + py + DISP; if (hg >= HH) hg -= HH;
          int wg = wx * WS_ + px + DISP; if (wg >= WW) wg -= WW;
          out[((size_t)(b * HH + hg) * WW + wg) * HIDDEN + t * 16 + n_] = acc[m][r];
        }
      }
  }
}

extern "C" void kernel_launch(void* const* d_in, const int* in_sizes, int n_in,
                              void* d_out, int out_size, void* d_ws, size_t ws_size,
                              hipStream_t stream) {
  const float* x     = (const float*)d_in[0];
  const float* w_qkv = (const float*)d_in[1];
  const float* b_qkv = (const float*)d_in[2];
  const float* pos   = (const float*)d_in[3];
  const float* w_out = (const float*)d_in[4];
  const float* b_out = (const float*)d_in[5];
  float* out = (float*)d_out;

  bf16* wfq = (bf16*)d_ws;                    // 27648 bf16
  bf16* wfo = wfq + (size_t)NFRAG_QKV * 8;    // 9216 bf16

  prep_weights_kernel<<<18, 256, 0, stream>>>(w_qkv, w_out, wfq, wfo);
  fused_swin_kernel<<<B_ * NW, 256, 0, stream>>>(x, wfq, wfo, b_qkv, b_out, pos, out);
}

// Round 2
// 129.074 us; speedup vs baseline: 1.1990x; 1.1216x over previous
//
#include <hip/hip_runtime.h>
#include <hip/hip_bf16.h>

using bf16 = __hip_bfloat16;
typedef __attribute__((ext_vector_type(8))) short short8;
typedef __attribute__((ext_vector_type(4))) float floatx4;

#define B_      32
#define HH      56
#define WW      56
#define HIDDEN  96
#define HEADS   3
#define HD      32
#define WS_     7
#define DISP    3
#define NWH     8
#define NWW     8
#define NW      64
#define WS2     49
#define NFRAG_QKV (3*6*3*64)                      /* 3456 lane-frags */
#define NFRAG_OUT (6*3*64)                        /* 1152 lane-frags */

// ---------------- Kernel 0: weight pre-swizzle into MFMA B-frag order -----
__global__ __launch_bounds__(256) void prep_weights_kernel(
    const float* __restrict__ w_qkv, const float* __restrict__ w_out,
    bf16* __restrict__ wfq, bf16* __restrict__ wfo) {
  int f = blockIdx.x * 256 + threadIdx.x;
  if (f < NFRAG_QKV) {
    int lane = f & 63, t = f >> 6;
    int kb = t % 3, t2 = t / 3, c6 = t2 % 6, ci = t2 / 6;
    int col = ci * 96 + c6 * 16 + (lane & 15);
    int k0 = kb * 32 + (lane >> 4) * 8;
    bf16 vals[8];
#pragma unroll
    for (int j = 0; j < 8; j++) vals[j] = __float2bfloat16(w_qkv[(k0 + j) * 288 + col]);
    *(short8*)&wfq[(size_t)f * 8] = *(const short8*)vals;
  } else if (f < NFRAG_QKV + NFRAG_OUT) {
    int fo = f - NFRAG_QKV;
    int lane = fo & 63, t = fo >> 6;
    int kb = t % 3, c6 = t / 3;
    int col = c6 * 16 + (lane & 15);
    int k0 = kb * 32 + (lane >> 4) * 8;
    bf16 vals[8];
#pragma unroll
    for (int j = 0; j < 8; j++) vals[j] = __float2bfloat16(w_out[(k0 + j) * 96 + col]);
    *(short8*)&wfo[(size_t)fo * 8] = *(const short8*)vals;
  }
}

__device__ inline unsigned short bf16_bits(float f) {
  unsigned u = __float_as_uint(f);
  unsigned r = u + 0x7fffu + ((u >> 16) & 1u);
  return (unsigned short)(r >> 16);
}

// ---------------- Fused kernel: one block per (batch, window) -------------
// LDS: slabA 15360 + slabB 15360 + vT 13824 + es 9216 = 53760 B -> 3 blk/CU.
// Barriers: 4 total (head loop is barrier-free: slabA[h] rows and es rows
// are wave-private; slabB/vT are read-only after phase 2b).
__global__ __launch_bounds__(256, 3) void fused_swin_kernel(
    const float* __restrict__ x,
    const bf16* __restrict__ wfq, const bf16* __restrict__ wfo,
    const float* __restrict__ b_qkv, const float* __restrict__ b_out,
    const float* __restrict__ pos_emb, float* __restrict__ out) {

  __shared__ unsigned short slabA[3][64][40];  // x (by 32-ch group) -> q -> attn out
  __shared__ unsigned short slabB[3][64][40];  // k (per head, [tok][d])
  __shared__ unsigned short vT[3][32][72];     // v transposed (per head, [d][tok])
  __shared__ unsigned short es[64][72];        // softmax probs (wave-private rows)

  const int blk = blockIdx.x;
  const int nw = blk & 63, b = blk >> 6;
  const int wy = nw >> 3, wx = nw & 7;
  const int tid = threadIdx.x;
  const int lane = tid & 63, wv = tid >> 6;
  const int n_ = lane & 15, quad = lane >> 4;

  // early prefetch of this wave's first QKV weight tile (hides L2 latency
  // under phase-1 staging)
  const short8* wfQ = (const short8*)wfq;
  short8 wcur0 = wfQ[(size_t)((wv * 3 + 0) * 64 + lane)];
  short8 wcur1 = wfQ[(size_t)((wv * 3 + 1) * 64 + lane)];
  short8 wcur2 = wfQ[(size_t)((wv * 3 + 2) * 64 + lane)];

  // ---- phase 1: shifted gather of x. 4 threads/row x 6 segs, one addr calc.
  {
    const int rowp = tid >> 2, s0 = tid & 3;
    const bool haveRow = rowp < WS2;
    const float* xrow = x;
    if (haveRow) {
      const int py = rowp / WS_, px = rowp % WS_;
      int h = wy * WS_ + py + DISP; if (h >= HH) h -= HH;
      int w = wx * WS_ + px + DISP; if (w >= WW) w -= WW;
      xrow = &x[((size_t)(b * HH + h) * WW + w) * HIDDEN];
    }
#pragma unroll
    for (int p = 0; p < 6; p++) {
      const int seg = s0 + 4 * p;                 // 0..23
      const int kb = seg >> 3, c4 = (seg & 7) << 2;
      ushort4 pk = (ushort4){0, 0, 0, 0};
      if (haveRow) {
        const float4 xv = *(const float4*)&xrow[seg * 4];
        pk.x = bf16_bits(xv.x); pk.y = bf16_bits(xv.y);
        pk.z = bf16_bits(xv.z); pk.w = bf16_bits(xv.w);
      }
      *(ushort4*)&slabA[kb][rowp][c4] = pk;
    }
  }

  // ---- geometry: pos-emb + mask folded per lane, straight from global ----
  const bool maskedw = (nw >= NW - NWW);
  const int i0 = 16 * wv + 4 * quad;
  float pelv[4][4];
#pragma unroll
  for (int r = 0; r < 4; r++) {
    const int i_r = i0 + r;
    const int iy = i_r / WS_, ix = i_r % WS_;
#pragma unroll
    for (int jt = 0; jt < 4; jt++) {
      const int j = 16 * jt + n_;
      const int jy = j / WS_, jx = j % WS_;
      int idx = (jy - iy + 6) * 13 + (jx - ix + 6);
      idx = idx < 0 ? 0 : (idx > 168 ? 168 : idx);
      const bool live = (j < WS2) && (i_r < WS2) &&
                        !(maskedw && ((i_r >= 28) != (j >= 28)));
      pelv[r][jt] = live ? pos_emb[idx] : -1e30f;
    }
  }
  __syncthreads();

  // ---- phase 2a: every wave reads A-frags for all 4 m-tiles ----
  short8 af[4][3];
#pragma unroll
  for (int m = 0; m < 4; m++)
#pragma unroll
    for (int kb = 0; kb < 3; kb++)
      af[m][kb] = *(const short8*)&slabA[kb][16 * m + n_][quad * 8];
  __syncthreads();  // slabA about to be overwritten by q

  // ---- phase 2b: QKV projection, N-split, 1-deep weight pipeline ----
  // q/k: swapped operands -> D[col][tok] -> vectorized [tok][d] b64 stores.
  // v:   normal order    -> D[tok][col] -> vectorized [d][tok] b64 stores.
  {
    int t = wv;
    while (t < 18) {
      const int tn = t + 4;
      short8 wn0 = wcur0, wn1 = wcur1, wn2 = wcur2;
      if (tn < 18) {
        wn0 = wfQ[(size_t)((tn * 3 + 0) * 64 + lane)];
        wn1 = wfQ[(size_t)((tn * 3 + 1) * 64 + lane)];
        wn2 = wfQ[(size_t)((tn * 3 + 2) * 64 + lane)];
      }
      const int ci = t / 6, c6 = t % 6, head = c6 >> 1;
      floatx4 acc[4];
      if (ci < 2) {
        const float4 bq = *(const float4*)&b_qkv[t * 16 + 4 * quad];
#pragma unroll
        for (int m = 0; m < 4; m++) acc[m] = (floatx4){bq.x, bq.y, bq.z, bq.w};
#pragma unroll
        for (int m = 0; m < 4; m++) {
          acc[m] = __builtin_amdgcn_mfma_f32_16x16x32_bf16(wcur0, af[m][0], acc[m], 0, 0, 0);
          acc[m] = __builtin_amdgcn_mfma_f32_16x16x32_bf16(wcur1, af[m][1], acc[m], 0, 0, 0);
          acc[m] = __builtin_amdgcn_mfma_f32_16x16x32_bf16(wcur2, af[m][2], acc[m], 0, 0, 0);
        }
        unsigned short (*tgt)[64][40] = (ci == 0) ? slabA : slabB;
        const int dc0 = ((c6 & 1) << 4) + 4 * quad;
#pragma unroll
        for (int m = 0; m < 4; m++) {
          ushort4 pk;
          pk.x = bf16_bits(acc[m][0]); pk.y = bf16_bits(acc[m][1]);
          pk.z = bf16_bits(acc[m][2]); pk.w = bf16_bits(acc[m][3]);
          *(ushort4*)&tgt[head][16 * m + n_][dc0] = pk;
        }
      } else {
        const float bias = b_qkv[t * 16 + n_];
#pragma unroll
        for (int m = 0; m < 4; m++) acc[m] = (floatx4){bias, bias, bias, bias};
#pragma unroll
        for (int m = 0; m < 4; m++) {
          acc[m] = __builtin_amdgcn_mfma_f32_16x16x32_bf16(af[m][0], wcur0, acc[m], 0, 0, 0);
          acc[m] = __builtin_amdgcn_mfma_f32_16x16x32_bf16(af[m][1], wcur1, acc[m], 0, 0, 0);
          acc[m] = __builtin_amdgcn_mfma_f32_16x16x32_bf16(af[m][2], wcur2, acc[m], 0, 0, 0);
        }
        const int dc = ((c6 & 1) << 4) + n_;
#pragma unroll
        for (int m = 0; m < 4; m++) {
          ushort4 pk;
          pk.x = bf16_bits(acc[m][0]); pk.y = bf16_bits(acc[m][1]);
          pk.z = bf16_bits(acc[m][2]); pk.w = bf16_bits(acc[m][3]);
          *(ushort4*)&vT[head][dc][16 * m + 4 * quad] = pk;
        }
      }
      wcur0 = wn0; wcur1 = wn1; wcur2 = wn2;
      t = tn;
    }
  }
  __syncthreads();

  // ---- phase 3: attention per head, barrier-free ----
  const float scale = 0.10206207261596575f;  // 96^-0.5
  const floatx4 zero4 = (floatx4){0.f, 0.f, 0.f, 0.f};
#pragma unroll
  for (int h = 0; h < HEADS; h++) {
    const short8 aq = *(const short8*)&slabA[h][16 * wv + n_][quad * 8];
    floatx4 sAcc[4];
#pragma unroll
    for (int jt = 0; jt < 4; jt++) {
      const short8 bk = *(const short8*)&slabB[h][16 * jt + n_][quad * 8];
      sAcc[jt] = __builtin_amdgcn_mfma_f32_16x16x32_bf16(aq, bk, zero4, 0, 0, 0);
    }

    float ei[4][4], rowsum[4];
#pragma unroll
    for (int r = 0; r < 4; r++) {
      rowsum[r] = 0.f;
#pragma unroll
      for (int jt = 0; jt < 4; jt++) {
        const float e = __expf(fmaf(sAcc[jt][r], scale, pelv[r][jt]));
        ei[r][jt] = e;
        rowsum[r] += e;
      }
    }
#pragma unroll
    for (int r = 0; r < 4; r++) {
      float s = rowsum[r];
      s += __shfl_xor(s, 1); s += __shfl_xor(s, 2);
      s += __shfl_xor(s, 4); s += __shfl_xor(s, 8);
      const float inv = s > 0.f ? 1.0f / s : 0.f;
#pragma unroll
      for (int jt = 0; jt < 4; jt++)
        es[i0 + r][16 * jt + n_] = bf16_bits(ei[r][jt] * inv);
    }

    // PV with swapped operands: D[d][tok] -> vectorized store of 4 d's/lane
    short8 ap[2];
#pragma unroll
    for (int kc = 0; kc < 2; kc++)
      ap[kc] = *(const short8*)&es[16 * wv + n_][32 * kc + quad * 8];
    floatx4 oAcc[2] = {zero4, zero4};
#pragma unroll
    for (int nt = 0; nt < 2; nt++)
#pragma unroll
      for (int kc = 0; kc < 2; kc++) {
        const short8 bv = *(const short8*)&vT[h][16 * nt + n_][32 * kc + quad * 8];
        oAcc[nt] = __builtin_amdgcn_mfma_f32_16x16x32_bf16(bv, ap[kc], oAcc[nt], 0, 0, 0);
      }
#pragma unroll
    for (int nt = 0; nt < 2; nt++) {
      ushort4 pk;
      pk.x = bf16_bits(oAcc[nt][0]); pk.y = bf16_bits(oAcc[nt][1]);
      pk.z = bf16_bits(oAcc[nt][2]); pk.w = bf16_bits(oAcc[nt][3]);
      *(ushort4*)&slabA[h][16 * wv + n_][16 * nt + 4 * quad] = pk;
    }
  }
  __syncthreads();

  // ---- phase 4: output projection, N-split, 1-deep weight pipeline ----
  short8 af2[4][3];
#pragma unroll
  for (int m = 0; m < 4; m++)
#pragma unroll
    for (int kb = 0; kb < 3; kb++)
      af2[m][kb] = *(const short8*)&slabA[kb][16 * m + n_][quad * 8];

  unsigned obase[4][4];
#pragma unroll
  for (int m = 0; m < 4; m++)
#pragma unroll
    for (int r = 0; r < 4; r++) {
      const int row = 16 * m + 4 * quad + r;
      const int py = row / WS_, px = row % WS_;
      int hg = wy * WS_ + py + DISP; if (hg >= HH) hg -= HH;
      int wg = wx * WS_ + px + DISP; if (wg >= WW) wg -= WW;
      obase[m][r] = (unsigned)(((b * HH + hg) * WW + wg) * HIDDEN + n_);
    }

  const short8* wfO = (const short8*)wfo;
  {
    int t = wv;
    short8 oc0 = wfO[(size_t)((t * 3 + 0) * 64 + lane)];
    short8 oc1 = wfO[(size_t)((t * 3 + 1) * 64 + lane)];
    short8 oc2 = wfO[(size_t)((t * 3 + 2) * 64 + lane)];
    while (t < 6) {
      const int tn = t + 4;
      short8 on0 = oc0, on1 = oc1, on2 = oc2;
      if (tn < 6) {
        on0 = wfO[(size_t)((tn * 3 + 0) * 64 + lane)];
        on1 = wfO[(size_t)((tn * 3 + 1) * 64 + lane)];
        on2 = wfO[(size_t)((tn * 3 + 2) * 64 + lane)];
      }
      const float bias = b_out[t * 16 + n_];
      floatx4 acc[4];
#pragma unroll
      for (int m = 0; m < 4; m++) acc[m] = (floatx4){bias, bias, bias, bias};
#pragma unroll
      for (int m = 0; m < 4; m++) {
        acc[m] = __builtin_amdgcn_mfma_f32_16x16x32_bf16(af2[m][0], oc0, acc[m], 0, 0, 0);
        acc[m] = __builtin_amdgcn_mfma_f32_16x16x32_bf16(af2[m][1], oc1, acc[m], 0, 0, 0);
        acc[m] = __builtin_amdgcn_mfma_f32_16x16x32_bf16(af2[m][2], oc2, acc[m], 0, 0, 0);
      }
#pragma unroll
      for (int m = 0; m < 4; m++)
#pragma unroll
        for (int r = 0; r < 4; r++) {
          if (16 * m + 4 * quad + r < WS2)
            out[(size_t)obase[m][r] + t * 16] = acc[m][r];
        }
      oc0 = on0; oc1 = on1; oc2 = on2;
      t = tn;
    }
  }
}

extern "C" void kernel_launch(void* const* d_in, const int* in_sizes, int n_in,
                              void* d_out, int out_size, void* d_ws, size_t ws_size,
                              hipStream_t stream) {
  const float* x     = (const float*)d_in[0];
  const float* w_qkv = (const float*)d_in[1];
  const float* b_qkv = (const float*)d_in[2];
  const float* pos   = (const float*)d_in[3];
  const float* w_out = (const float*)d_in[4];
  const float* b_out = (const float*)d_in[5];
  float* out = (float*)d_out;

  bf16* wfq = (bf16*)d_ws;                    // 27648 bf16
  bf16* wfo = wfq + (size_t)NFRAG_QKV * 8;    // 9216 bf16

  prep_weights_kernel<<<18, 256, 0, stream>>>(w_qkv, w_out, wfq, wfo);
  fused_swin_kernel<<<B_ * NW, 256, 0, stream>>>(x, wfq, wfo, b_qkv, b_out, pos, out);
}

// Round 4
// 126.458 us; speedup vs baseline: 1.2238x; 1.0207x over previous
//
#include <hip/hip_runtime.h>
#include <hip/hip_bf16.h>

using bf16 = __hip_bfloat16;
typedef __attribute__((ext_vector_type(8))) short short8;
typedef __attribute__((ext_vector_type(4))) float floatx4;

#define B_      32
#define HH      56
#define WW      56
#define HIDDEN  96
#define HEADS   3
#define HD      32
#define WS_     7
#define DISP    3
#define NWH     8
#define NWW     8
#define NW      64
#define WS2     49
#define NFRAG_QKV (3*6*3*64)                      /* 3456 lane-frags */
#define NFRAG_OUT (6*3*64)                        /* 1152 lane-frags */
#define NPEL      (2*64*64)                       /* 8192 table entries */

__device__ inline unsigned short bf16_bits(float f) {
  unsigned u = __float_as_uint(f);
  unsigned r = u + 0x7fffu + ((u >> 16) & 1u);
  return (unsigned short)(r >> 16);
}
__device__ inline unsigned packbf(float lo, float hi) {
  return (unsigned)bf16_bits(lo) | ((unsigned)bf16_bits(hi) << 16);
}

// ---------------- Kernel 0: weight pre-swizzle + pos/mask table -----------
__global__ __launch_bounds__(256) void prep_kernel(
    const float* __restrict__ w_qkv, const float* __restrict__ w_out,
    const float* __restrict__ pos_emb,
    bf16* __restrict__ wfq, bf16* __restrict__ wfo, float* __restrict__ pelT) {
  int f = blockIdx.x * 256 + threadIdx.x;
  if (f < NFRAG_QKV) {
    int lane = f & 63, t = f >> 6;
    int kb = t % 3, t2 = t / 3, c6 = t2 % 6, ci = t2 / 6;
    int col = ci * 96 + c6 * 16 + (lane & 15);
    int k0 = kb * 32 + (lane >> 4) * 8;
    bf16 vals[8];
#pragma unroll
    for (int j = 0; j < 8; j++) vals[j] = __float2bfloat16(w_qkv[(k0 + j) * 288 + col]);
    *(short8*)&wfq[(size_t)f * 8] = *(const short8*)vals;
  } else if (f < NFRAG_QKV + NFRAG_OUT) {
    int fo = f - NFRAG_QKV;
    int lane = fo & 63, t = fo >> 6;
    int kb = t % 3, c6 = t / 3;
    int col = c6 * 16 + (lane & 15);
    int k0 = kb * 32 + (lane >> 4) * 8;
    bf16 vals[8];
#pragma unroll
    for (int j = 0; j < 8; j++) vals[j] = __float2bfloat16(w_out[(k0 + j) * 96 + col]);
    *(short8*)&wfo[(size_t)fo * 8] = *(const short8*)vals;
  } else {
    int p = f - (NFRAG_QKV + NFRAG_OUT);
    if (p < NPEL) {
      int mk = p >> 12, i = (p >> 6) & 63, j = p & 63;   // i = q-token, j = k-token
      int iy = i / WS_, ix = i % WS_, jy = j / WS_, jx = j % WS_;
      int idx = (jy - iy + 6) * 13 + (jx - ix + 6);
      idx = idx < 0 ? 0 : (idx > 168 ? 168 : idx);
      bool live = (i < WS2) && (j < WS2) && !(mk && ((i >= 28) != (j >= 28)));
      pelT[p] = live ? pos_emb[idx] : -1e30f;
    }
  }
}

// ---------------- Fused kernel: one block per (batch, window) -------------
// LDS: slabA 12288 + slabB 12288 + vT 13824 = 38400 B -> 4 blocks/CU.
// K is stored PERMUTED in slabB (row s holds token pi(s), pi(16jt+4q+r) =
// 32(jt&1)+4(jt>>1)+8q+r) so the swapped-QK^T output layout is exactly the
// K=32 PV B-fragment layout: P never leaves registers, zero shuffles.
__global__ __launch_bounds__(256, 4) void fused_swin_kernel(
    const float* __restrict__ x,
    const bf16* __restrict__ wfq, const bf16* __restrict__ wfo,
    const float* __restrict__ b_qkv, const float* __restrict__ b_out,
    const float* __restrict__ pelT, float* __restrict__ out) {

  __shared__ unsigned short slabA[3][64][32];  // x (32-ch groups) -> q -> attn out
  __shared__ unsigned short slabB[3][64][32];  // k (per head, permuted rows, [tok][d])
  __shared__ unsigned short vT[3][32][72];     // v transposed (per head, [d][tok])

  const int blk = blockIdx.x;
  const int nw = blk & 63, b = blk >> 6;
  const int wy = nw >> 3, wx = nw & 7;
  const int tid = threadIdx.x;
  const int lane = tid & 63, wv = tid >> 6;
  const int n_ = lane & 15, quad = lane >> 4;

  // early prefetch of this wave's first QKV weight tile
  const short8* wfQ = (const short8*)wfq;
  short8 wcur0 = wfQ[(size_t)((wv * 3 + 0) * 64 + lane)];
  short8 wcur1 = wfQ[(size_t)((wv * 3 + 1) * 64 + lane)];
  short8 wcur2 = wfQ[(size_t)((wv * 3 + 2) * 64 + lane)];

  // ---- phase 1: shifted gather of x. 4 threads/row x 6 segs ----
  {
    const int rowp = tid >> 2, s0 = tid & 3;
    const bool haveRow = rowp < WS2;
    const float* xrow = x;
    if (haveRow) {
      const int py = rowp / WS_, px = rowp % WS_;
      int h = wy * WS_ + py + DISP; if (h >= HH) h -= HH;
      int w = wx * WS_ + px + DISP; if (w >= WW) w -= WW;
      xrow = &x[((size_t)(b * HH + h) * WW + w) * HIDDEN];
    }
#pragma unroll
    for (int p = 0; p < 6; p++) {
      const int seg = s0 + 4 * p;                 // 0..23
      const int kb = seg >> 3, c4 = (seg & 7) << 2;
      uint2 pk = (uint2){0u, 0u};
      if (haveRow) {
        const float4 xv = *(const float4*)&xrow[seg * 4];
        pk.x = packbf(xv.x, xv.y);
        pk.y = packbf(xv.z, xv.w);
      }
      *(uint2*)&slabA[kb][rowp][c4] = pk;
    }
  }

  // ---- pos-emb + mask from table, k-index follows the K permutation:
  //      pelv[jt][r] = pelT[i=16wv+n_][j = 32(jt&1)+4(jt>>1)+8quad+r] ----
  const bool maskedw = (nw >= NW - NWW);
  float pelv[4][4];
  {
    const float4* pt4 = (const float4*)&pelT[(maskedw ? 4096 : 0) + (16 * wv + n_) * 64];
#pragma unroll
    for (int jt = 0; jt < 4; jt++) {
      const float4 p4 = pt4[8 * (jt & 1) + (jt >> 1) + 2 * quad];
      pelv[jt][0] = p4.x; pelv[jt][1] = p4.y;
      pelv[jt][2] = p4.z; pelv[jt][3] = p4.w;
    }
  }
  __syncthreads();

  // ---- phase 2a: every wave reads A-frags for all 4 m-tiles ----
  short8 af[4][3];
#pragma unroll
  for (int m = 0; m < 4; m++)
#pragma unroll
    for (int kb = 0; kb < 3; kb++)
      af[m][kb] = *(const short8*)&slabA[kb][16 * m + n_][quad * 8];
  __syncthreads();  // slabA about to be overwritten by q

  // ---- phase 2b: QKV projection, N-split, 1-deep weight pipeline ----
  {
    // permuted destination row offset for K stores (token t=16m+n_ ->
    // row 32*t2 + 16*t5 + 8*t4 + 4*t3 + t[1:0] = rB + 8m)
    const int rB = 32 * ((n_ >> 2) & 1) + 4 * (n_ >> 3) + (n_ & 3);
    int t = wv;
    while (t < 18) {
      const int tn = t + 4;
      short8 wn0 = wcur0, wn1 = wcur1, wn2 = wcur2;
      if (tn < 18) {
        wn0 = wfQ[(size_t)((tn * 3 + 0) * 64 + lane)];
        wn1 = wfQ[(size_t)((tn * 3 + 1) * 64 + lane)];
        wn2 = wfQ[(size_t)((tn * 3 + 2) * 64 + lane)];
      }
      const int ci = t / 6, c6 = t % 6, head = c6 >> 1;
      floatx4 acc[4];
      if (ci < 2) {   // q,k: swapped -> D[d][tok] -> [tok][d] vector stores
        const float4 bq = *(const float4*)&b_qkv[t * 16 + 4 * quad];
#pragma unroll
        for (int m = 0; m < 4; m++) acc[m] = (floatx4){bq.x, bq.y, bq.z, bq.w};
#pragma unroll
        for (int m = 0; m < 4; m++) {
          acc[m] = __builtin_amdgcn_mfma_f32_16x16x32_bf16(wcur0, af[m][0], acc[m], 0, 0, 0);
          acc[m] = __builtin_amdgcn_mfma_f32_16x16x32_bf16(wcur1, af[m][1], acc[m], 0, 0, 0);
          acc[m] = __builtin_amdgcn_mfma_f32_16x16x32_bf16(wcur2, af[m][2], acc[m], 0, 0, 0);
        }
        const int dc0 = ((c6 & 1) << 4) + 4 * quad;
        if (ci == 0) {          // q: natural rows
#pragma unroll
          for (int m = 0; m < 4; m++) {
            uint2 st;
            st.x = packbf(acc[m][0], acc[m][1]);
            st.y = packbf(acc[m][2], acc[m][3]);
            *(uint2*)&slabA[head][16 * m + n_][dc0] = st;
          }
        } else {                // k: permuted rows
#pragma unroll
          for (int m = 0; m < 4; m++) {
            uint2 st;
            st.x = packbf(acc[m][0], acc[m][1]);
            st.y = packbf(acc[m][2], acc[m][3]);
            *(uint2*)&slabB[head][rB + 8 * m][dc0] = st;
          }
        }
      } else {        // v: normal -> D[tok][d] -> [d][tok] vector stores
        const float bias = b_qkv[t * 16 + n_];
#pragma unroll
        for (int m = 0; m < 4; m++) acc[m] = (floatx4){bias, bias, bias, bias};
#pragma unroll
        for (int m = 0; m < 4; m++) {
          acc[m] = __builtin_amdgcn_mfma_f32_16x16x32_bf16(af[m][0], wcur0, acc[m], 0, 0, 0);
          acc[m] = __builtin_amdgcn_mfma_f32_16x16x32_bf16(af[m][1], wcur1, acc[m], 0, 0, 0);
          acc[m] = __builtin_amdgcn_mfma_f32_16x16x32_bf16(af[m][2], wcur2, acc[m], 0, 0, 0);
        }
        const int dc = ((c6 & 1) << 4) + n_;
#pragma unroll
        for (int m = 0; m < 4; m++) {
          uint2 st;
          st.x = packbf(acc[m][0], acc[m][1]);
          st.y = packbf(acc[m][2], acc[m][3]);
          *(uint2*)&vT[head][dc][16 * m + 4 * quad] = st;
        }
      }
      wcur0 = wn0; wcur1 = wn1; wcur2 = wn2;
      t = tn;
    }
  }
  __syncthreads();

  // ---- phase 3: attention per head, barrier-free, P fully in registers --
  const float scale = 0.10206207261596575f;  // 96^-0.5
  const floatx4 zero4 = (floatx4){0.f, 0.f, 0.f, 0.f};
#pragma unroll
  for (int h = 0; h < HEADS; h++) {
    // swapped QK^T: sAcc[jt][r] = S[tok=32(jt&1)+4(jt>>1)+8quad+r][q=16wv+n_]
    const short8 aq = *(const short8*)&slabA[h][16 * wv + n_][quad * 8];
    floatx4 sAcc[4];
#pragma unroll
    for (int jt = 0; jt < 4; jt++) {
      const short8 bk = *(const short8*)&slabB[h][16 * jt + n_][quad * 8];
      sAcc[jt] = __builtin_amdgcn_mfma_f32_16x16x32_bf16(bk, aq, zero4, 0, 0, 0);
    }

    float ei[4][4];
    float s = 0.f;
#pragma unroll
    for (int jt = 0; jt < 4; jt++)
#pragma unroll
      for (int r = 0; r < 4; r++) {
        const float e = __expf(fmaf(sAcc[jt][r], scale, pelv[jt][r]));
        ei[jt][r] = e;
        s += e;
      }
    s += __shfl_xor(s, 16);
    s += __shfl_xor(s, 32);
    const float invq = s > 0.f ? 1.0f / s : 0.f;

    // lane-local PV B-frags thanks to the K permutation:
    // apf[kc] element j holds P[32kc+8quad+j][q=16wv+n_]
    unsigned pk2[4][2];
#pragma unroll
    for (int jt = 0; jt < 4; jt++) {
      pk2[jt][0] = packbf(ei[jt][0], ei[jt][1]);
      pk2[jt][1] = packbf(ei[jt][2], ei[jt][3]);
    }
    short8 apf[2];
#pragma unroll
    for (int kc = 0; kc < 2; kc++) {
      union { unsigned u[4]; short8 s8; } fu;
      fu.u[0] = pk2[kc][0];
      fu.u[1] = pk2[kc][1];
      fu.u[2] = pk2[2 + kc][0];
      fu.u[3] = pk2[2 + kc][1];
      apf[kc] = fu.s8;
    }

    // PV swapped: D[d][q]; invq is lane-local for this lane's q-token
    floatx4 oAcc[2] = {zero4, zero4};
#pragma unroll
    for (int nt = 0; nt < 2; nt++)
#pragma unroll
      for (int kc = 0; kc < 2; kc++) {
        const short8 bv = *(const short8*)&vT[h][16 * nt + n_][32 * kc + quad * 8];
        oAcc[nt] = __builtin_amdgcn_mfma_f32_16x16x32_bf16(bv, apf[kc], oAcc[nt], 0, 0, 0);
      }
#pragma unroll
    for (int nt = 0; nt < 2; nt++) {
      uint2 st;
      st.x = packbf(oAcc[nt][0] * invq, oAcc[nt][1] * invq);
      st.y = packbf(oAcc[nt][2] * invq, oAcc[nt][3] * invq);
      *(uint2*)&slabA[h][16 * wv + n_][16 * nt + 4 * quad] = st;
    }
  }
  __syncthreads();

  // ---- phase 4: output projection, N-split, 1-deep weight pipeline ----
  short8 af2[4][3];
#pragma unroll
  for (int m = 0; m < 4; m++)
#pragma unroll
    for (int kb = 0; kb < 3; kb++)
      af2[m][kb] = *(const short8*)&slabA[kb][16 * m + n_][quad * 8];

  unsigned obase[4][4];
#pragma unroll
  for (int m = 0; m < 4; m++)
#pragma unroll
    for (int r = 0; r < 4; r++) {
      const int row = 16 * m + 4 * quad + r;
      const int py = row / WS_, px = row % WS_;
      int hg = wy * WS_ + py + DISP; if (hg >= HH) hg -= HH;
      int wg = wx * WS_ + px + DISP; if (wg >= WW) wg -= WW;
      obase[m][r] = (unsigned)(((b * HH + hg) * WW + wg) * HIDDEN + n_);
    }

  const short8* wfO = (const short8*)wfo;
  {
    int t = wv;
    short8 oc0 = wfO[(size_t)((t * 3 + 0) * 64 + lane)];
    short8 oc1 = wfO[(size_t)((t * 3 + 1) * 64 + lane)];
    short8 oc2 = wfO[(size_t)((t * 3 + 2) * 64 + lane)];
    while (t < 6) {
      const int tn = t + 4;
      short8 on0 = oc0, on1 = oc1, on2 = oc2;
      if (tn < 6) {
        on0 = wfO[(size_t)((tn * 3 + 0) * 64 + lane)];
        on1 = wfO[(size_t)((tn * 3 + 1) * 64 + lane)];
        on2 = wfO[(size_t)((tn * 3 + 2) * 64 + lane)];
      }
      const float bias = b_out[t * 16 + n_];
      floatx4 acc[4];
#pragma unroll
      for (int m = 0; m < 4; m++) acc[m] = (floatx4){bias, bias, bias, bias};
#pragma unroll
      for (int m = 0; m < 4; m++) {
        acc[m] = __builtin_amdgcn_mfma_f32_16x16x32_bf16(af2[m][0], oc0, acc[m], 0, 0, 0);
        acc[m] = __builtin_amdgcn_mfma_f32_16x16x32_bf16(af2[m][1], oc1, acc[m], 0, 0, 0);
        acc[m] = __builtin_amdgcn_mfma_f32_16x16x32_bf16(af2[m][2], oc2, acc[m], 0, 0, 0);
      }
#pragma unroll
      for (int m = 0; m < 4; m++)
#pragma unroll
        for (int r = 0; r < 4; r++) {
          if (16 * m + 4 * quad + r < WS2)
            out[(size_t)obase[m][r] + t * 16] = acc[m][r];
        }
      oc0 = on0; oc1 = on1; oc2 = on2;
      t = tn;
    }
  }
}

extern "C" void kernel_launch(void* const* d_in, const int* in_sizes, int n_in,
                              void* d_out, int out_size, void* d_ws, size_t ws_size,
                              hipStream_t stream) {
  const float* x     = (const float*)d_in[0];
  const float* w_qkv = (const float*)d_in[1];
  const float* b_qkv = (const float*)d_in[2];
  const float* pos   = (const float*)d_in[3];
  const float* w_out = (const float*)d_in[4];
  const float* b_out = (const float*)d_in[5];
  float* out = (float*)d_out;

  bf16* wfq = (bf16*)d_ws;                                  // 27648 bf16
  bf16* wfo = wfq + (size_t)NFRAG_QKV * 8;                  // 9216 bf16
  float* pelT = (float*)((char*)d_ws + (size_t)(NFRAG_QKV + NFRAG_OUT) * 8 * 2);

  prep_kernel<<<50, 256, 0, stream>>>(w_qkv, w_out, pos, wfq, wfo, pelT);
  fused_swin_kernel<<<B_ * NW, 256, 0, stream>>>(x, wfq, wfo, b_qkv, b_out, pelT, out);
}

// Round 5
// 121.271 us; speedup vs baseline: 1.2762x; 1.0428x over previous
//
#include <hip/hip_runtime.h>
#include <hip/hip_bf16.h>

using bf16 = __hip_bfloat16;
typedef __attribute__((ext_vector_type(8))) short short8;
typedef __attribute__((ext_vector_type(4))) float floatx4;

#define B_      32
#define HH      56
#define WW      56
#define HIDDEN  96
#define HEADS   3
#define HD      32
#define WS_     7
#define DISP    3
#define NWH     8
#define NWW     8
#define NW      64
#define WS2     49
#define NFRAG_QKV (3*6*3*64)                      /* 3456 lane-frags */
#define NFRAG_OUT (6*3*64)                        /* 1152 lane-frags */
#define NPEL      (2*64*64)                       /* 8192 table entries */

__device__ inline unsigned short bf16_bits(float f) {
  unsigned u = __float_as_uint(f);
  unsigned r = u + 0x7fffu + ((u >> 16) & 1u);
  return (unsigned short)(r >> 16);
}

// packed f32x2 -> bf16x2 (RNE), single instruction on gfx950 (T12, m214)
__device__ inline unsigned cvtpk(float lo, float hi) {
  unsigned r;
  asm("v_cvt_pk_bf16_f32 %0, %1, %2" : "=v"(r) : "v"(lo), "v"(hi));
  return r;
}

// granule-XOR swizzled pointer into a [64][32]-ushort plane (64 B rows).
// Applied on BOTH write and read sides -> bijective, 16B-align preserved.
__device__ inline unsigned short* swz(const unsigned short* plane, int row, int boff) {
  return (unsigned short*)((char*)plane + (row << 6) + (boff ^ ((row & 3) << 4)));
}

// ---------------- Kernel 0: weight pre-swizzle + pos/mask table -----------
__global__ __launch_bounds__(256) void prep_kernel(
    const float* __restrict__ w_qkv, const float* __restrict__ w_out,
    const float* __restrict__ pos_emb,
    bf16* __restrict__ wfq, bf16* __restrict__ wfo, float* __restrict__ pelT) {
  int f = blockIdx.x * 256 + threadIdx.x;
  if (f < NFRAG_QKV) {
    int lane = f & 63, t = f >> 6;
    int kb = t % 3, t2 = t / 3, c6 = t2 % 6, ci = t2 / 6;
    int col = ci * 96 + c6 * 16 + (lane & 15);
    int k0 = kb * 32 + (lane >> 4) * 8;
    bf16 vals[8];
#pragma unroll
    for (int j = 0; j < 8; j++) vals[j] = __float2bfloat16(w_qkv[(k0 + j) * 288 + col]);
    *(short8*)&wfq[(size_t)f * 8] = *(const short8*)vals;
  } else if (f < NFRAG_QKV + NFRAG_OUT) {
    int fo = f - NFRAG_QKV;
    int lane = fo & 63, t = fo >> 6;
    int kb = t % 3, c6 = t / 3;
    int col = c6 * 16 + (lane & 15);
    int k0 = kb * 32 + (lane >> 4) * 8;
    bf16 vals[8];
#pragma unroll
    for (int j = 0; j < 8; j++) vals[j] = __float2bfloat16(w_out[(k0 + j) * 96 + col]);
    *(short8*)&wfo[(size_t)fo * 8] = *(const short8*)vals;
  } else {
    int p = f - (NFRAG_QKV + NFRAG_OUT);
    if (p < NPEL) {
      int mk = p >> 12, i = (p >> 6) & 63, j = p & 63;   // i = q-token, j = k-token
      int iy = i / WS_, ix = i % WS_, jy = j / WS_, jx = j % WS_;
      int idx = (jy - iy + 6) * 13 + (jx - ix + 6);
      idx = idx < 0 ? 0 : (idx > 168 ? 168 : idx);
      bool live = (i < WS2) && (j < WS2) && !(mk && ((i >= 28) != (j >= 28)));
      pelT[p] = live ? pos_emb[idx] : -1e30f;
    }
  }
}

// ---------------- Fused kernel: one block per (batch, window) -------------
// LDS: slabA 12288 + slabB 12288 + vT 13824 = 38400 B -> 4 blocks/CU.
// Slabs are granule-XOR swizzled (boff ^ (row&3)<<4): b128 reads stay
// bank-balanced AND the 8B wave-writes drop from 8-way to balanced 4-way.
// K stored PERMUTED in slabB (pi(16jt+4q+r) = 32(jt&1)+4(jt>>1)+8q+r) so
// the swapped-QK^T output IS the K=32 PV B-frag layout: P stays in regs.
__global__ __launch_bounds__(256, 4) void fused_swin_kernel(
    const float* __restrict__ x,
    const bf16* __restrict__ wfq, const bf16* __restrict__ wfo,
    const float* __restrict__ b_qkv, const float* __restrict__ b_out,
    const float* __restrict__ pelT, float* __restrict__ out) {

  __shared__ unsigned short slabA[3][64][32];  // x (32-ch groups) -> q -> attn out
  __shared__ unsigned short slabB[3][64][32];  // k (per head, permuted rows)
  __shared__ unsigned short vT[3][32][72];     // v transposed (per head, [d][tok])

  const int blk = blockIdx.x;
  const int nw = blk & 63, b = blk >> 6;
  const int wy = nw >> 3, wx = nw & 7;
  const int tid = threadIdx.x;
  const int lane = tid & 63, wv = tid >> 6;
  const int n_ = lane & 15, quad = lane >> 4;

  // early prefetch of this wave's first QKV weight tile
  const short8* wfQ = (const short8*)wfq;
  short8 wcur0 = wfQ[(size_t)((wv * 3 + 0) * 64 + lane)];
  short8 wcur1 = wfQ[(size_t)((wv * 3 + 1) * 64 + lane)];
  short8 wcur2 = wfQ[(size_t)((wv * 3 + 2) * 64 + lane)];

  // ---- phase 1: shifted gather of x. 4 threads/row x 6 segs ----
  {
    const int rowp = tid >> 2, s0 = tid & 3;
    const bool haveRow = rowp < WS2;
    const float* xrow = x;
    if (haveRow) {
      const int py = rowp / WS_, px = rowp % WS_;
      int h = wy * WS_ + py + DISP; if (h >= HH) h -= HH;
      int w = wx * WS_ + px + DISP; if (w >= WW) w -= WW;
      xrow = &x[((size_t)(b * HH + h) * WW + w) * HIDDEN];
    }
#pragma unroll
    for (int p = 0; p < 6; p++) {
      const int seg = s0 + 4 * p;                 // 0..23
      const int kb = seg >> 3;
      uint2 pk = (uint2){0u, 0u};
      if (haveRow) {
        const float4 xv = *(const float4*)&xrow[seg * 4];
        pk.x = cvtpk(xv.x, xv.y);
        pk.y = cvtpk(xv.z, xv.w);
      }
      *(uint2*)swz(&slabA[kb][0][0], rowp, (seg & 7) * 8) = pk;
    }
  }

  // ---- pos-emb + mask from table, k-index follows the K permutation ----
  const bool maskedw = (nw >= NW - NWW);
  float pelv[4][4];
  {
    const float4* pt4 = (const float4*)&pelT[(maskedw ? 4096 : 0) + (16 * wv + n_) * 64];
#pragma unroll
    for (int jt = 0; jt < 4; jt++) {
      const float4 p4 = pt4[8 * (jt & 1) + (jt >> 1) + 2 * quad];
      pelv[jt][0] = p4.x; pelv[jt][1] = p4.y;
      pelv[jt][2] = p4.z; pelv[jt][3] = p4.w;
    }
  }
  __syncthreads();

  // ---- phase 2a: every wave reads A-frags for all 4 m-tiles ----
  short8 af[4][3];
#pragma unroll
  for (int m = 0; m < 4; m++)
#pragma unroll
    for (int kb = 0; kb < 3; kb++)
      af[m][kb] = *(const short8*)swz(&slabA[kb][0][0], 16 * m + n_, quad * 16);
  __syncthreads();  // slabA about to be overwritten by q

  // ---- phase 2b: QKV projection, N-split, 1-deep weight pipeline ----
  {
    // permuted destination row offset for K stores
    const int rB = 32 * ((n_ >> 2) & 1) + 4 * (n_ >> 3) + (n_ & 3);
    int t = wv;
    while (t < 18) {
      const int tn = t + 4;
      short8 wn0 = wcur0, wn1 = wcur1, wn2 = wcur2;
      if (tn < 18) {
        wn0 = wfQ[(size_t)((tn * 3 + 0) * 64 + lane)];
        wn1 = wfQ[(size_t)((tn * 3 + 1) * 64 + lane)];
        wn2 = wfQ[(size_t)((tn * 3 + 2) * 64 + lane)];
      }
      const int ci = t / 6, c6 = t % 6, head = c6 >> 1;
      floatx4 acc[4];
      if (ci < 2) {   // q,k: swapped -> D[d][tok] -> [tok][d] vector stores
        const float4 bq = *(const float4*)&b_qkv[t * 16 + 4 * quad];
#pragma unroll
        for (int m = 0; m < 4; m++) acc[m] = (floatx4){bq.x, bq.y, bq.z, bq.w};
#pragma unroll
        for (int m = 0; m < 4; m++) {
          acc[m] = __builtin_amdgcn_mfma_f32_16x16x32_bf16(wcur0, af[m][0], acc[m], 0, 0, 0);
          acc[m] = __builtin_amdgcn_mfma_f32_16x16x32_bf16(wcur1, af[m][1], acc[m], 0, 0, 0);
          acc[m] = __builtin_amdgcn_mfma_f32_16x16x32_bf16(wcur2, af[m][2], acc[m], 0, 0, 0);
        }
        const int boff = ((c6 & 1) << 5) + quad * 8;
        if (ci == 0) {          // q: natural rows
#pragma unroll
          for (int m = 0; m < 4; m++) {
            uint2 st;
            st.x = cvtpk(acc[m][0], acc[m][1]);
            st.y = cvtpk(acc[m][2], acc[m][3]);
            *(uint2*)swz(&slabA[head][0][0], 16 * m + n_, boff) = st;
          }
        } else {                // k: permuted rows
#pragma unroll
          for (int m = 0; m < 4; m++) {
            uint2 st;
            st.x = cvtpk(acc[m][0], acc[m][1]);
            st.y = cvtpk(acc[m][2], acc[m][3]);
            *(uint2*)swz(&slabB[head][0][0], rB + 8 * m, boff) = st;
          }
        }
      } else {        // v: normal -> D[tok][d] -> [d][tok] vector stores
        const float bias = b_qkv[t * 16 + n_];
#pragma unroll
        for (int m = 0; m < 4; m++) acc[m] = (floatx4){bias, bias, bias, bias};
#pragma unroll
        for (int m = 0; m < 4; m++) {
          acc[m] = __builtin_amdgcn_mfma_f32_16x16x32_bf16(af[m][0], wcur0, acc[m], 0, 0, 0);
          acc[m] = __builtin_amdgcn_mfma_f32_16x16x32_bf16(af[m][1], wcur1, acc[m], 0, 0, 0);
          acc[m] = __builtin_amdgcn_mfma_f32_16x16x32_bf16(af[m][2], wcur2, acc[m], 0, 0, 0);
        }
        const int dc = ((c6 & 1) << 4) + n_;
#pragma unroll
        for (int m = 0; m < 4; m++) {
          uint2 st;
          st.x = cvtpk(acc[m][0], acc[m][1]);
          st.y = cvtpk(acc[m][2], acc[m][3]);
          *(uint2*)&vT[head][dc][16 * m + 4 * quad] = st;
        }
      }
      wcur0 = wn0; wcur1 = wn1; wcur2 = wn2;
      t = tn;
    }
  }
  __syncthreads();

  // ---- phase 3: attention per head, barrier-free, P fully in registers --
  const float scale = 0.10206207261596575f;  // 96^-0.5
  const floatx4 zero4 = (floatx4){0.f, 0.f, 0.f, 0.f};
#pragma unroll
  for (int h = 0; h < HEADS; h++) {
    // swapped QK^T: sAcc[jt][r] = S[tok=32(jt&1)+4(jt>>1)+8quad+r][q=16wv+n_]
    const short8 aq = *(const short8*)swz(&slabA[h][0][0], 16 * wv + n_, quad * 16);
    floatx4 sAcc[4];
    __builtin_amdgcn_s_setprio(1);
#pragma unroll
    for (int jt = 0; jt < 4; jt++) {
      const short8 bk = *(const short8*)swz(&slabB[h][0][0], 16 * jt + n_, quad * 16);
      sAcc[jt] = __builtin_amdgcn_mfma_f32_16x16x32_bf16(bk, aq, zero4, 0, 0, 0);
    }
    __builtin_amdgcn_s_setprio(0);

    float ei[4][4];
    float s = 0.f;
#pragma unroll
    for (int jt = 0; jt < 4; jt++)
#pragma unroll
      for (int r = 0; r < 4; r++) {
        const float e = __expf(fmaf(sAcc[jt][r], scale, pelv[jt][r]));
        ei[jt][r] = e;
        s += e;
      }
    s += __shfl_xor(s, 16);
    s += __shfl_xor(s, 32);
    const float invq = s > 0.f ? __builtin_amdgcn_rcpf(s) : 0.f;

    // lane-local PV B-frags thanks to the K permutation
    unsigned pk2[4][2];
#pragma unroll
    for (int jt = 0; jt < 4; jt++) {
      pk2[jt][0] = cvtpk(ei[jt][0], ei[jt][1]);
      pk2[jt][1] = cvtpk(ei[jt][2], ei[jt][3]);
    }
    short8 apf[2];
#pragma unroll
    for (int kc = 0; kc < 2; kc++) {
      union { unsigned u[4]; short8 s8; } fu;
      fu.u[0] = pk2[kc][0];
      fu.u[1] = pk2[kc][1];
      fu.u[2] = pk2[2 + kc][0];
      fu.u[3] = pk2[2 + kc][1];
      apf[kc] = fu.s8;
    }

    // PV swapped: D[d][q]; invq is lane-local for this lane's q-token
    floatx4 oAcc[2] = {zero4, zero4};
    __builtin_amdgcn_s_setprio(1);
#pragma unroll
    for (int nt = 0; nt < 2; nt++)
#pragma unroll
      for (int kc = 0; kc < 2; kc++) {
        const short8 bv = *(const short8*)&vT[h][16 * nt + n_][32 * kc + quad * 8];
        oAcc[nt] = __builtin_amdgcn_mfma_f32_16x16x32_bf16(bv, apf[kc], oAcc[nt], 0, 0, 0);
      }
    __builtin_amdgcn_s_setprio(0);
#pragma unroll
    for (int nt = 0; nt < 2; nt++) {
      uint2 st;
      st.x = cvtpk(oAcc[nt][0] * invq, oAcc[nt][1] * invq);
      st.y = cvtpk(oAcc[nt][2] * invq, oAcc[nt][3] * invq);
      *(uint2*)swz(&slabA[h][0][0], 16 * wv + n_, nt * 32 + quad * 8) = st;
    }
  }
  __syncthreads();

  // ---- phase 4: output projection, N-split, 1-deep weight pipeline ----
  short8 af2[4][3];
#pragma unroll
  for (int m = 0; m < 4; m++)
#pragma unroll
    for (int kb = 0; kb < 3; kb++)
      af2[m][kb] = *(const short8*)swz(&slabA[kb][0][0], 16 * m + n_, quad * 16);

  unsigned obase[4][4];
#pragma unroll
  for (int m = 0; m < 4; m++)
#pragma unroll
    for (int r = 0; r < 4; r++) {
      const int row = 16 * m + 4 * quad + r;
      const int py = row / WS_, px = row % WS_;
      int hg = wy * WS_ + py + DISP; if (hg >= HH) hg -= HH;
      int wg = wx * WS_ + px + DISP; if (wg >= WW) wg -= WW;
      obase[m][r] = (unsigned)(((b * HH + hg) * WW + wg) * HIDDEN + n_);
    }

  const short8* wfO = (const short8*)wfo;
  {
    int t = wv;
    short8 oc0 = wfO[(size_t)((t * 3 + 0) * 64 + lane)];
    short8 oc1 = wfO[(size_t)((t * 3 + 1) * 64 + lane)];
    short8 oc2 = wfO[(size_t)((t * 3 + 2) * 64 + lane)];
    while (t < 6) {
      const int tn = t + 4;
      short8 on0 = oc0, on1 = oc1, on2 = oc2;
      if (tn < 6) {
        on0 = wfO[(size_t)((tn * 3 + 0) * 64 + lane)];
        on1 = wfO[(size_t)((tn * 3 + 1) * 64 + lane)];
        on2 = wfO[(size_t)((tn * 3 + 2) * 64 + lane)];
      }
      const float bias = b_out[t * 16 + n_];
      floatx4 acc[4];
#pragma unroll
      for (int m = 0; m < 4; m++) acc[m] = (floatx4){bias, bias, bias, bias};
#pragma unroll
      for (int m = 0; m < 4; m++) {
        acc[m] = __builtin_amdgcn_mfma_f32_16x16x32_bf16(af2[m][0], oc0, acc[m], 0, 0, 0);
        acc[m] = __builtin_amdgcn_mfma_f32_16x16x32_bf16(af2[m][1], oc1, acc[m], 0, 0, 0);
        acc[m] = __builtin_amdgcn_mfma_f32_16x16x32_bf16(af2[m][2], oc2, acc[m], 0, 0, 0);
      }
#pragma unroll
      for (int m = 0; m < 4; m++)
#pragma unroll
        for (int r = 0; r < 4; r++) {
          if (16 * m + 4 * quad + r < WS2)
            out[(size_t)obase[m][r] + t * 16] = acc[m][r];
        }
      oc0 = on0; oc1 = on1; oc2 = on2;
      t = tn;
    }
  }
}

extern "C" void kernel_launch(void* const* d_in, const int* in_sizes, int n_in,
                              void* d_out, int out_size, void* d_ws, size_t ws_size,
                              hipStream_t stream) {
  const float* x     = (const float*)d_in[0];
  const float* w_qkv = (const float*)d_in[1];
  const float* b_qkv = (const float*)d_in[2];
  const float* pos   = (const float*)d_in[3];
  const float* w_out = (const float*)d_in[4];
  const float* b_out = (const float*)d_in[5];
  float* out = (float*)d_out;

  bf16* wfq = (bf16*)d_ws;                                  // 27648 bf16
  bf16* wfo = wfq + (size_t)NFRAG_QKV * 8;                  // 9216 bf16
  float* pelT = (float*)((char*)d_ws + (size_t)(NFRAG_QKV + NFRAG_OUT) * 8 * 2);

  prep_kernel<<<50, 256, 0, stream>>>(w_qkv, w_out, pos, wfq, wfo, pelT);
  fused_swin_kernel<<<B_ * NW, 256, 0, stream>>>(x, wfq, wfo, b_qkv, b_out, pelT, out);
}